// Round 1
// baseline (969.273 us; speedup 1.0000x reference)
//
#include <hip/hip_runtime.h>
#include <math.h>

#define DEV __device__ __forceinline__

DEV float lrelu(float x){ return x > 0.f ? x : 0.01f*x; }
DEV float elu1(float x){ return x > 0.f ? x : __expf(x)-1.f; }

DEV int lower_bound_i(const int* __restrict__ a, int n, int key){
  int lo = 0, hi = n;
  while (lo < hi){ int mid = (lo+hi)>>1; if (a[mid] < key) lo = mid+1; else hi = mid; }
  return lo;
}

// ---------------- GEMM: C[M,128] = act(A[M,K] @ W[K,128] (+bias)) ----------------
// Block 256 = 4 waves. Each wave: 16 rows x 128 cols (2 cols per lane).
// A rows read via wave-uniform addresses (SGPR broadcast); W staged in LDS.
template<int K, bool EPI>
__global__ __launch_bounds__(256) void gemm128(const float* __restrict__ A,
    const float* __restrict__ W, const float* __restrict__ bias,
    float* __restrict__ C, int M)
{
  __shared__ float sW[K*128];
  const int tid = threadIdx.x;
  #pragma unroll
  for (int i = tid; i < K*32; i += 256)
    ((float4*)sW)[i] = ((const float4*)W)[i];
  __syncthreads();

  const int lane = tid & 63;
  const int wv = ((int)__builtin_amdgcn_readfirstlane(tid)) >> 6;
  const int row0 = (blockIdx.x*4 + wv)*16;

  const float* Ap[16];
  #pragma unroll
  for (int r = 0; r < 16; ++r){
    int rr = row0 + r; rr = rr < M ? rr : M-1;
    Ap[r] = A + (size_t)rr * K;
  }
  float acc[16][2];
  #pragma unroll
  for (int r = 0; r < 16; ++r){ acc[r][0] = 0.f; acc[r][1] = 0.f; }

  const float2* wrow = ((const float2*)sW) + lane;
  #pragma unroll 4
  for (int k = 0; k < K; ++k){
    float2 w = wrow[(size_t)k*64];
    #pragma unroll
    for (int r = 0; r < 16; ++r){
      float a = Ap[r][k];
      acc[r][0] = fmaf(a, w.x, acc[r][0]);
      acc[r][1] = fmaf(a, w.y, acc[r][1]);
    }
  }
  float2 bb = make_float2(0.f, 0.f);
  if constexpr (EPI) bb = *(const float2*)(bias + lane*2);
  #pragma unroll
  for (int r = 0; r < 16; ++r){
    int rr = row0 + r;
    if (rr < M){
      float v0 = acc[r][0], v1 = acc[r][1];
      if constexpr (EPI){ v0 = lrelu(v0 + bb.x); v1 = lrelu(v1 + bb.y); }
      *(float2*)(C + (size_t)rr*128 + lane*2) = make_float2(v0, v1);
    }
  }
}

// ---------------- per-row dots: outa[r]=X[r]·va, outb[r]=X[r]·vb ----------------
__global__ __launch_bounds__(256) void rowdots(const float* __restrict__ X,
    const float* __restrict__ va, const float* __restrict__ vb,
    float* __restrict__ outa, float* __restrict__ outb, int M)
{
  const int lane = threadIdx.x & 63;
  const int wv = threadIdx.x >> 6;
  const int row = blockIdx.x*4 + wv;
  if (row >= M) return;
  float2 x = *(const float2*)(X + (size_t)row*128 + lane*2);
  float2 a = *(const float2*)(va + lane*2);
  float2 b = *(const float2*)(vb + lane*2);
  float da = x.x*a.x + x.y*a.y;
  float db = x.x*b.x + x.y*b.y;
  #pragma unroll
  for (int o = 32; o; o >>= 1){
    da += __shfl_down(da, o, 64);
    db += __shfl_down(db, o, 64);
  }
  if (lane == 0){ outa[row] = da; outb[row] = db; }
}

// ---------------- CSR build ----------------
__global__ void hist_k(const int* __restrict__ dstv, int* __restrict__ deg, int E){
  int e = blockIdx.x*256 + threadIdx.x;
  if (e < E) atomicAdd(&deg[dstv[e]], 1);
}

__global__ void scan_sum(const int* __restrict__ deg, int* __restrict__ bsum, int n){
  __shared__ int s4[4];
  int i = blockIdx.x*256 + threadIdx.x;
  int v = (i < n) ? deg[i] : 0;
  #pragma unroll
  for (int o = 32; o; o >>= 1) v += __shfl_down(v, o, 64);
  if ((threadIdx.x & 63) == 0) s4[threadIdx.x >> 6] = v;
  __syncthreads();
  if (threadIdx.x == 0) bsum[blockIdx.x] = s4[0]+s4[1]+s4[2]+s4[3];
}

__global__ void scan_blocksums(int* __restrict__ bsum, int nb){
  __shared__ int s[512];
  int t = threadIdx.x;
  s[t] = (t < nb) ? bsum[t] : 0;
  __syncthreads();
  for (int o = 1; o < 512; o <<= 1){
    int v = s[t];
    int u = (t >= o) ? s[t-o] : 0;
    __syncthreads();
    s[t] = v + u;
    __syncthreads();
  }
  if (t < nb) bsum[t] = t ? s[t-1] : 0;   // exclusive
}

__global__ void scan_final(const int* __restrict__ deg, const int* __restrict__ boff,
    int* __restrict__ rp, int* __restrict__ cur, int n, int E)
{
  __shared__ int wsum[4];
  int i = blockIdx.x*256 + threadIdx.x;
  int lane = threadIdx.x & 63, wv = threadIdx.x >> 6;
  int v = (i < n) ? deg[i] : 0;
  int inc = v;
  #pragma unroll
  for (int o = 1; o < 64; o <<= 1){
    int u = __shfl_up(inc, o, 64);
    if (lane >= o) inc += u;
  }
  if (lane == 63) wsum[wv] = inc;
  __syncthreads();
  int woff = boff[blockIdx.x];
  for (int wq = 0; wq < wv; ++wq) woff += wsum[wq];
  int excl = woff + inc - v;
  if (i < n){ rp[i] = excl; cur[i] = excl; }
  if (blockIdx.x == 0 && threadIdx.x == 0) rp[n] = E;
}

__global__ void scatter_k(const int* __restrict__ dstv, int* __restrict__ cur,
                          int* __restrict__ eids, int E){
  int e = blockIdx.x*256 + threadIdx.x;
  if (e < E){
    int p = atomicAdd(&cur[dstv[e]], 1);
    eids[p] = e;
  }
}

// ---------------- fused segment softmax + aggregation (one wave per dst node) ----------------
__global__ __launch_bounds__(256) void gat_agg(const int* __restrict__ srcv,
    const int* __restrict__ eids, const int* __restrict__ rp,
    const float* __restrict__ asn, const float* __restrict__ adn,
    const float* __restrict__ hs, const float* __restrict__ bias,
    float* __restrict__ out, int Nn)
{
  const int lane = threadIdx.x & 63;
  const int wv = threadIdx.x >> 6;
  const int d = blockIdx.x*4 + wv;
  if (d >= Nn) return;
  const int lo = rp[d], hi = rp[d+1];
  const int deg = hi - lo;
  float acc0 = 0.f, acc1 = 0.f;
  if (deg > 0){
    const float ad = adn[d];
    if (deg <= 64){
      int sid = 0; float lg = -1e30f;
      if (lane < deg){
        int eid = eids[lo + lane];
        sid = srcv[eid];
        lg = lrelu(asn[sid] + ad);
      }
      float m = lg;
      #pragma unroll
      for (int o = 32; o; o >>= 1) m = fmaxf(m, __shfl_xor(m, o, 64));
      float p = (lane < deg) ? __expf(lg - m) : 0.f;
      float s = p;
      #pragma unroll
      for (int o = 32; o; o >>= 1) s += __shfl_xor(s, o, 64);
      float inv = 1.f / (s + 1e-16f);
      float alpha = p * inv;
      for (int e = 0; e < deg; ++e){
        float a = __shfl(alpha, e, 64);
        int sd = __shfl(sid, e, 64);
        float2 v = *(const float2*)(hs + (size_t)sd*128 + lane*2);
        acc0 = fmaf(a, v.x, acc0);
        acc1 = fmaf(a, v.y, acc1);
      }
    } else {
      // rare generic path
      float m = -1e30f;
      for (int e = lane; e < deg; e += 64){
        int sid = srcv[eids[lo+e]];
        m = fmaxf(m, lrelu(asn[sid] + ad));
      }
      #pragma unroll
      for (int o = 32; o; o >>= 1) m = fmaxf(m, __shfl_xor(m, o, 64));
      float s = 0.f;
      for (int e = lane; e < deg; e += 64){
        int sid = srcv[eids[lo+e]];
        s += __expf(lrelu(asn[sid] + ad) - m);
      }
      #pragma unroll
      for (int o = 32; o; o >>= 1) s += __shfl_xor(s, o, 64);
      float inv = 1.f / (s + 1e-16f);
      for (int e = 0; e < deg; ++e){
        int sid = srcv[eids[lo+e]];
        float a = __expf(lrelu(asn[sid] + ad) - m) * inv;
        float2 v = *(const float2*)(hs + (size_t)sid*128 + lane*2);
        acc0 = fmaf(a, v.x, acc0);
        acc1 = fmaf(a, v.y, acc1);
      }
    }
  }
  float2 bb = *(const float2*)(bias + lane*2);
  float o0 = elu1(acc0 + bb.x);
  float o1 = elu1(acc1 + bb.y);
  *(float2*)(out + (size_t)d*128 + lane*2) = make_float2(o0, o1);
}

// ---------------- graph pooling: pooled[g] = relu(sum over nodes of graph g) ----------------
__global__ __launch_bounds__(128) void pool_relu(const float* __restrict__ h,
    const int* __restrict__ batch, float* __restrict__ pooled, int Nn)
{
  const int g = blockIdx.x;
  const int c = threadIdx.x;   // 0..127
  __shared__ int sb[2];
  if (c < 2) sb[c] = lower_bound_i(batch, Nn, g + c);
  __syncthreads();
  const int lo = sb[0], hi = sb[1];
  float s = 0.f;
  for (int i = lo; i < hi; ++i) s += h[(size_t)i*128 + c];
  pooled[(size_t)g*128 + c] = fmaxf(s, 0.f);
}

// ---------------- molecular GAT aggregate + final linear (fused) ----------------
__global__ __launch_bounds__(128) void mol_agg(const float* __restrict__ as2,
    const float* __restrict__ ad2, const float* __restrict__ hs2,
    const int* __restrict__ batch, const float* __restrict__ bias,
    const float* __restrict__ W2, const float* __restrict__ b2,
    float* __restrict__ out, int Nn)
{
  const int g = blockIdx.x;
  const int c = threadIdx.x;   // 0..127 (one feature per thread)
  __shared__ int sb[2];
  __shared__ float red[2];
  if (c < 2) sb[c] = lower_bound_i(batch, Nn, g + c);
  __syncthreads();
  const int lo = sb[0], hi = sb[1];
  const float ad = ad2[g];

  // pass 1: max logit
  float mt = -1e30f;
  for (int i = lo + c; i < hi; i += 128) mt = fmaxf(mt, lrelu(as2[i] + ad));
  #pragma unroll
  for (int o = 32; o; o >>= 1) mt = fmaxf(mt, __shfl_xor(mt, o, 64));
  if ((c & 63) == 0) red[c >> 6] = mt;
  __syncthreads();
  const float m = fmaxf(red[0], red[1]);

  // pass 2: sum of exp
  float st = 0.f;
  for (int i = lo + c; i < hi; i += 128) st += __expf(lrelu(as2[i] + ad) - m);
  #pragma unroll
  for (int o = 32; o; o >>= 1) st += __shfl_xor(st, o, 64);
  __syncthreads();
  if ((c & 63) == 0) red[c >> 6] = st;
  __syncthreads();
  const float inv = 1.f / (red[0] + red[1] + 1e-16f);

  // pass 3: weighted feature sum (thread owns one column)
  float acc = 0.f;
  for (int i = lo; i < hi; ++i){
    float wgt = __expf(lrelu(as2[i] + ad) - m) * inv;
    acc = fmaf(wgt, hs2[(size_t)i*128 + c], acc);
  }
  float v = elu1(acc + bias[c]);

  // fused final linear: out[g] = sum_c v[c]*W2[c] + b2
  float r = v * W2[c];
  #pragma unroll
  for (int o = 32; o; o >>= 1) r += __shfl_xor(r, o, 64);
  __syncthreads();
  if ((c & 63) == 0) red[c >> 6] = r;
  __syncthreads();
  if (c == 0) out[g] = red[0] + red[1] + b2[0];
}

extern "C" void kernel_launch(void* const* d_in, const int* in_sizes, int n_in,
                              void* d_out, int out_size, void* d_ws, size_t ws_size,
                              hipStream_t stream)
{
  const float* x      = (const float*)d_in[0];
  const int*   ei     = (const int*)  d_in[1];
  const int*   batch  = (const int*)  d_in[2];
  const float* W1     = (const float*)d_in[3];
  const float* b1     = (const float*)d_in[4];
  const float* gW     = (const float*)d_in[5];
  const float* g_asrc = (const float*)d_in[6];
  const float* g_adst = (const float*)d_in[7];
  const float* g_b    = (const float*)d_in[8];
  const float* mW     = (const float*)d_in[9];
  const float* m_asrc = (const float*)d_in[10];
  const float* m_adst = (const float*)d_in[11];
  const float* m_b    = (const float*)d_in[12];
  const float* W2     = (const float*)d_in[13];
  const float* b2     = (const float*)d_in[14];

  const int Nn = in_sizes[0] / 64;            // 100000
  const int E  = in_sizes[1] / 2;             // 400000
  const int G  = out_size;                    // 5000
  const int NL = in_sizes[5] / (128*128);     // 3
  const int* srcv = ei;
  const int* dstv = ei + E;

  char* w = (char*)d_ws;
  float* hA     = (float*)w; w += (size_t)Nn*128*4;
  float* hB     = (float*)w; w += (size_t)Nn*128*4;
  float* pooled = (float*)w; w += (size_t)G*128*4;
  float* hd2    = (float*)w; w += (size_t)G*128*4;
  float* asN    = (float*)w; w += (size_t)Nn*4;
  float* adN    = (float*)w; w += (size_t)Nn*4;
  int*   deg    = (int*)w;   w += (size_t)Nn*4;
  int*   rp     = (int*)w;   w += (size_t)(Nn+64)*4;
  int*   cur    = (int*)w;   w += (size_t)Nn*4;
  int*   eids   = (int*)w;   w += (size_t)E*4;
  int*   bsum   = (int*)w;   w += 4096;

  const int nscan = (Nn + 255)/256;

  // ---- CSR build (once; reused by all GAT layers) ----
  hipMemsetAsync(deg, 0, (size_t)Nn*4, stream);
  hist_k<<<(E+255)/256, 256, 0, stream>>>(dstv, deg, E);
  scan_sum<<<nscan, 256, 0, stream>>>(deg, bsum, Nn);
  scan_blocksums<<<1, 512, 0, stream>>>(bsum, nscan);
  scan_final<<<nscan, 256, 0, stream>>>(deg, bsum, rp, cur, Nn, E);
  scatter_k<<<(E+255)/256, 256, 0, stream>>>(dstv, cur, eids, E);

  // ---- lin1 + leaky_relu ----
  gemm128<64, true><<<(Nn+63)/64, 256, 0, stream>>>(x, W1, b1, hA, Nn);

  // ---- 3 GAT layers ----
  for (int l = 0; l < NL; ++l){
    gemm128<128, false><<<(Nn+63)/64, 256, 0, stream>>>(hA, gW + (size_t)l*128*128, nullptr, hB, Nn);
    rowdots<<<(Nn+3)/4, 256, 0, stream>>>(hB, g_asrc + l*128, g_adst + l*128, asN, adN, Nn);
    gat_agg<<<(Nn+3)/4, 256, 0, stream>>>(srcv, eids, rp, asN, adN, hB, g_b + l*128, hA, Nn);
  }

  // ---- readout ----
  pool_relu<<<G, 128, 0, stream>>>(hA, batch, pooled, Nn);
  gemm128<128, false><<<(Nn+63)/64, 256, 0, stream>>>(hA, mW, nullptr, hB, Nn);     // hs2
  rowdots<<<(Nn+3)/4, 256, 0, stream>>>(hB, m_asrc, m_asrc, asN, asN, Nn);          // as2
  gemm128<128, false><<<(G+63)/64, 256, 0, stream>>>(pooled, mW, nullptr, hd2, G);  // hd2
  rowdots<<<(G+3)/4, 256, 0, stream>>>(hd2, m_adst, m_adst, adN, adN, G);           // ad2
  mol_agg<<<G, 128, 0, stream>>>(asN, adN, hB, batch, m_b, W2, b2, (float*)d_out, Nn);
}

// Round 2
// 547.076 us; speedup vs baseline: 1.7717x; 1.7717x over previous
//
#include <hip/hip_runtime.h>
#include <math.h>

#define DEV __device__ __forceinline__

DEV float lrelu(float x){ return x > 0.f ? x : 0.01f*x; }
DEV float elu1(float x){ return x > 0.f ? x : __expf(x)-1.f; }

DEV int lower_bound_i(const int* __restrict__ a, int n, int key){
  int lo = 0, hi = n;
  while (lo < hi){ int mid = (lo+hi)>>1; if (a[mid] < key) lo = mid+1; else hi = mid; }
  return lo;
}

// ---------------- GEMM: C[M,128] = act(A[M,K] @ W[K,128] (+bias)) ----------------
// Block 256 threads = 64-row x 128-col tile. A tile staged in LDS (32 KiB @K=128).
// Thread (cg = tid&31, rg = tid>>5) owns 8 rows x 4 cols -> 128 indep FMAs/k-step.
// Optional fused epilogue: per-row dots with va/vb (attention projections).
template<int K, bool BIAS_LRELU, bool DOTS>
__global__ __launch_bounds__(256, 4) void gemm128(
    const float* __restrict__ A, const float* __restrict__ Wg,
    const float* __restrict__ bias, const float* __restrict__ va,
    const float* __restrict__ vb, float* __restrict__ C,
    float* __restrict__ outa, float* __restrict__ outb, int M)
{
  __shared__ float4 sA[16*K];           // 64 rows x K floats
  const int tid = threadIdx.x;
  const int row0 = blockIdx.x * 64;
  const float4* Ag4 = (const float4*)A;
  const int maxf4 = (M*(K/4)) - 1;
  #pragma unroll
  for (int i = 0; i < (16*K)/256; ++i){
    int li = i*256 + tid;
    int gi = row0*(K/4) + li;
    sA[li] = Ag4[gi <= maxf4 ? gi : maxf4];
  }
  __syncthreads();

  const int cg = tid & 31;              // cols 4*cg .. 4*cg+3
  const int rg = tid >> 5;              // rows rg*8 .. rg*8+7
  float4 acc[8];
  #pragma unroll
  for (int r = 0; r < 8; ++r) acc[r] = make_float4(0.f,0.f,0.f,0.f);

  const float4* wp = ((const float4*)Wg) + cg;   // W row-major [K][128]
  const float4* ap = sA + rg*8*(K/4);
  #pragma unroll 4
  for (int ks = 0; ks < K/4; ++ks){
    float4 w0 = wp[0];
    float4 w1 = wp[32];
    float4 w2 = wp[64];
    float4 w3 = wp[96];
    wp += 128;
    #pragma unroll
    for (int r = 0; r < 8; ++r){
      float4 a = ap[r*(K/4)];
      acc[r].x = fmaf(a.x, w0.x, acc[r].x);
      acc[r].y = fmaf(a.x, w0.y, acc[r].y);
      acc[r].z = fmaf(a.x, w0.z, acc[r].z);
      acc[r].w = fmaf(a.x, w0.w, acc[r].w);
      acc[r].x = fmaf(a.y, w1.x, acc[r].x);
      acc[r].y = fmaf(a.y, w1.y, acc[r].y);
      acc[r].z = fmaf(a.y, w1.z, acc[r].z);
      acc[r].w = fmaf(a.y, w1.w, acc[r].w);
      acc[r].x = fmaf(a.z, w2.x, acc[r].x);
      acc[r].y = fmaf(a.z, w2.y, acc[r].y);
      acc[r].z = fmaf(a.z, w2.z, acc[r].z);
      acc[r].w = fmaf(a.z, w2.w, acc[r].w);
      acc[r].x = fmaf(a.w, w3.x, acc[r].x);
      acc[r].y = fmaf(a.w, w3.y, acc[r].y);
      acc[r].z = fmaf(a.w, w3.z, acc[r].z);
      acc[r].w = fmaf(a.w, w3.w, acc[r].w);
    }
    ap += 1;
  }

  float4 bb = make_float4(0.f,0.f,0.f,0.f);
  if constexpr (BIAS_LRELU) bb = ((const float4*)bias)[cg];
  #pragma unroll
  for (int r = 0; r < 8; ++r){
    int row = row0 + rg*8 + r;
    if (row < M){
      float4 v = acc[r];
      if constexpr (BIAS_LRELU){
        v.x = lrelu(v.x + bb.x);
        v.y = lrelu(v.y + bb.y);
        v.z = lrelu(v.z + bb.z);
        v.w = lrelu(v.w + bb.w);
        acc[r] = v;
      }
      *(float4*)(C + (size_t)row*128 + cg*4) = v;
    }
  }

  if constexpr (DOTS){
    float4 a4 = ((const float4*)va)[cg];
    float4 b4 = ((const float4*)vb)[cg];
    #pragma unroll
    for (int r = 0; r < 8; ++r){
      float da = acc[r].x*a4.x + acc[r].y*a4.y + acc[r].z*a4.z + acc[r].w*a4.w;
      float db = acc[r].x*b4.x + acc[r].y*b4.y + acc[r].z*b4.z + acc[r].w*b4.w;
      #pragma unroll
      for (int o = 16; o; o >>= 1){
        da += __shfl_xor(da, o, 64);
        db += __shfl_xor(db, o, 64);
      }
      int row = row0 + rg*8 + r;
      if (cg == 0 && row < M){ outa[row] = da; outb[row] = db; }
    }
  }
}

// ---------------- CSR build ----------------
__global__ void hist_k(const int* __restrict__ dstv, int* __restrict__ deg, int E){
  int e = blockIdx.x*256 + threadIdx.x;
  if (e < E) atomicAdd(&deg[dstv[e]], 1);
}

__global__ void scan_sum(const int* __restrict__ deg, int* __restrict__ bsum, int n){
  __shared__ int s4[4];
  int i = blockIdx.x*256 + threadIdx.x;
  int v = (i < n) ? deg[i] : 0;
  #pragma unroll
  for (int o = 32; o; o >>= 1) v += __shfl_down(v, o, 64);
  if ((threadIdx.x & 63) == 0) s4[threadIdx.x >> 6] = v;
  __syncthreads();
  if (threadIdx.x == 0) bsum[blockIdx.x] = s4[0]+s4[1]+s4[2]+s4[3];
}

__global__ void scan_blocksums(int* __restrict__ bsum, int nb){
  __shared__ int s[512];
  int t = threadIdx.x;
  s[t] = (t < nb) ? bsum[t] : 0;
  __syncthreads();
  for (int o = 1; o < 512; o <<= 1){
    int v = s[t];
    int u = (t >= o) ? s[t-o] : 0;
    __syncthreads();
    s[t] = v + u;
    __syncthreads();
  }
  if (t < nb) bsum[t] = t ? s[t-1] : 0;   // exclusive
}

__global__ void scan_final(const int* __restrict__ deg, const int* __restrict__ boff,
    int* __restrict__ rp, int* __restrict__ cur, int n, int E)
{
  __shared__ int wsum[4];
  int i = blockIdx.x*256 + threadIdx.x;
  int lane = threadIdx.x & 63, wv = threadIdx.x >> 6;
  int v = (i < n) ? deg[i] : 0;
  int inc = v;
  #pragma unroll
  for (int o = 1; o < 64; o <<= 1){
    int u = __shfl_up(inc, o, 64);
    if (lane >= o) inc += u;
  }
  if (lane == 63) wsum[wv] = inc;
  __syncthreads();
  int woff = boff[blockIdx.x];
  for (int wq = 0; wq < wv; ++wq) woff += wsum[wq];
  int excl = woff + inc - v;
  if (i < n){ rp[i] = excl; cur[i] = excl; }
  if (blockIdx.x == 0 && threadIdx.x == 0) rp[n] = E;
}

__global__ void scatter_k(const int* __restrict__ dstv, int* __restrict__ cur,
                          int* __restrict__ eids, int E){
  int e = blockIdx.x*256 + threadIdx.x;
  if (e < E){
    int p = atomicAdd(&cur[dstv[e]], 1);
    eids[p] = e;
  }
}

// ---------------- fused segment softmax + aggregation (one wave per dst node) ----------------
__global__ __launch_bounds__(256) void gat_agg(const int* __restrict__ srcv,
    const int* __restrict__ eids, const int* __restrict__ rp,
    const float* __restrict__ asn, const float* __restrict__ adn,
    const float* __restrict__ hs, const float* __restrict__ bias,
    float* __restrict__ out, int Nn)
{
  const int lane = threadIdx.x & 63;
  const int wv = threadIdx.x >> 6;
  const int d = blockIdx.x*4 + wv;
  if (d >= Nn) return;
  const int lo = rp[d], hi = rp[d+1];
  const int deg = hi - lo;
  float acc0 = 0.f, acc1 = 0.f;
  if (deg > 0){
    const float ad = adn[d];
    if (deg <= 64){
      int sid = 0; float lg = -1e30f;
      if (lane < deg){
        int eid = eids[lo + lane];
        sid = srcv[eid];
        lg = lrelu(asn[sid] + ad);
      }
      float m = lg;
      #pragma unroll
      for (int o = 32; o; o >>= 1) m = fmaxf(m, __shfl_xor(m, o, 64));
      float p = (lane < deg) ? __expf(lg - m) : 0.f;
      float s = p;
      #pragma unroll
      for (int o = 32; o; o >>= 1) s += __shfl_xor(s, o, 64);
      float inv = 1.f / (s + 1e-16f);
      float alpha = p * inv;
      for (int e = 0; e < deg; ++e){
        float a = __shfl(alpha, e, 64);
        int sd = __shfl(sid, e, 64);
        float2 v = *(const float2*)(hs + (size_t)sd*128 + lane*2);
        acc0 = fmaf(a, v.x, acc0);
        acc1 = fmaf(a, v.y, acc1);
      }
    } else {
      float m = -1e30f;
      for (int e = lane; e < deg; e += 64){
        int sid = srcv[eids[lo+e]];
        m = fmaxf(m, lrelu(asn[sid] + ad));
      }
      #pragma unroll
      for (int o = 32; o; o >>= 1) m = fmaxf(m, __shfl_xor(m, o, 64));
      float s = 0.f;
      for (int e = lane; e < deg; e += 64){
        int sid = srcv[eids[lo+e]];
        s += __expf(lrelu(asn[sid] + ad) - m);
      }
      #pragma unroll
      for (int o = 32; o; o >>= 1) s += __shfl_xor(s, o, 64);
      float inv = 1.f / (s + 1e-16f);
      for (int e = 0; e < deg; ++e){
        int sid = srcv[eids[lo+e]];
        float a = __expf(lrelu(asn[sid] + ad) - m) * inv;
        float2 v = *(const float2*)(hs + (size_t)sid*128 + lane*2);
        acc0 = fmaf(a, v.x, acc0);
        acc1 = fmaf(a, v.y, acc1);
      }
    }
  }
  float2 bb = *(const float2*)(bias + lane*2);
  float o0 = elu1(acc0 + bb.x);
  float o1 = elu1(acc1 + bb.y);
  *(float2*)(out + (size_t)d*128 + lane*2) = make_float2(o0, o1);
}

// ---------------- graph pooling: pooled[g] = relu(sum over nodes of graph g) ----------------
__global__ __launch_bounds__(128) void pool_relu(const float* __restrict__ h,
    const int* __restrict__ batch, float* __restrict__ pooled, int Nn)
{
  const int g = blockIdx.x;
  const int c = threadIdx.x;   // 0..127
  __shared__ int sb[2];
  if (c < 2) sb[c] = lower_bound_i(batch, Nn, g + c);
  __syncthreads();
  const int lo = sb[0], hi = sb[1];
  float s = 0.f;
  for (int i = lo; i < hi; ++i) s += h[(size_t)i*128 + c];
  pooled[(size_t)g*128 + c] = fmaxf(s, 0.f);
}

// ---------------- molecular GAT aggregate + final linear (fused) ----------------
__global__ __launch_bounds__(128) void mol_agg(const float* __restrict__ as2,
    const float* __restrict__ ad2, const float* __restrict__ hs2,
    const int* __restrict__ batch, const float* __restrict__ bias,
    const float* __restrict__ W2, const float* __restrict__ b2,
    float* __restrict__ out, int Nn)
{
  const int g = blockIdx.x;
  const int c = threadIdx.x;   // 0..127 (one feature per thread)
  __shared__ int sb[2];
  __shared__ float red[2];
  if (c < 2) sb[c] = lower_bound_i(batch, Nn, g + c);
  __syncthreads();
  const int lo = sb[0], hi = sb[1];
  const float ad = ad2[g];

  float mt = -1e30f;
  for (int i = lo + c; i < hi; i += 128) mt = fmaxf(mt, lrelu(as2[i] + ad));
  #pragma unroll
  for (int o = 32; o; o >>= 1) mt = fmaxf(mt, __shfl_xor(mt, o, 64));
  if ((c & 63) == 0) red[c >> 6] = mt;
  __syncthreads();
  const float m = fmaxf(red[0], red[1]);

  float st = 0.f;
  for (int i = lo + c; i < hi; i += 128) st += __expf(lrelu(as2[i] + ad) - m);
  #pragma unroll
  for (int o = 32; o; o >>= 1) st += __shfl_xor(st, o, 64);
  __syncthreads();
  if ((c & 63) == 0) red[c >> 6] = st;
  __syncthreads();
  const float inv = 1.f / (red[0] + red[1] + 1e-16f);

  float acc = 0.f;
  for (int i = lo; i < hi; ++i){
    float wgt = __expf(lrelu(as2[i] + ad) - m) * inv;
    acc = fmaf(wgt, hs2[(size_t)i*128 + c], acc);
  }
  float v = elu1(acc + bias[c]);

  float r = v * W2[c];
  #pragma unroll
  for (int o = 32; o; o >>= 1) r += __shfl_xor(r, o, 64);
  __syncthreads();
  if ((c & 63) == 0) red[c >> 6] = r;
  __syncthreads();
  if (c == 0) out[g] = red[0] + red[1] + b2[0];
}

extern "C" void kernel_launch(void* const* d_in, const int* in_sizes, int n_in,
                              void* d_out, int out_size, void* d_ws, size_t ws_size,
                              hipStream_t stream)
{
  const float* x      = (const float*)d_in[0];
  const int*   ei     = (const int*)  d_in[1];
  const int*   batch  = (const int*)  d_in[2];
  const float* W1     = (const float*)d_in[3];
  const float* b1     = (const float*)d_in[4];
  const float* gW     = (const float*)d_in[5];
  const float* g_asrc = (const float*)d_in[6];
  const float* g_adst = (const float*)d_in[7];
  const float* g_b    = (const float*)d_in[8];
  const float* mW     = (const float*)d_in[9];
  const float* m_asrc = (const float*)d_in[10];
  const float* m_adst = (const float*)d_in[11];
  const float* m_b    = (const float*)d_in[12];
  const float* W2     = (const float*)d_in[13];
  const float* b2     = (const float*)d_in[14];

  const int Nn = in_sizes[0] / 64;            // 100000
  const int E  = in_sizes[1] / 2;             // 400000
  const int G  = out_size;                    // 5000
  const int NL = in_sizes[5] / (128*128);     // 3
  const int* srcv = ei;
  const int* dstv = ei + E;

  char* w = (char*)d_ws;
  float* hA     = (float*)w; w += (size_t)Nn*128*4;
  float* hB     = (float*)w; w += (size_t)Nn*128*4;
  float* pooled = (float*)w; w += (size_t)G*128*4;
  float* hd2    = (float*)w; w += (size_t)G*128*4;
  float* asN    = (float*)w; w += (size_t)Nn*4;
  float* adN    = (float*)w; w += (size_t)Nn*4;
  int*   deg    = (int*)w;   w += (size_t)Nn*4;
  int*   rp     = (int*)w;   w += (size_t)(Nn+64)*4;
  int*   cur    = (int*)w;   w += (size_t)Nn*4;
  int*   eids   = (int*)w;   w += (size_t)E*4;
  int*   bsum   = (int*)w;   w += 4096;

  const int nscan = (Nn + 255)/256;

  // ---- CSR build (once; reused by all GAT layers) ----
  hipMemsetAsync(deg, 0, (size_t)Nn*4, stream);
  hist_k<<<(E+255)/256, 256, 0, stream>>>(dstv, deg, E);
  scan_sum<<<nscan, 256, 0, stream>>>(deg, bsum, Nn);
  scan_blocksums<<<1, 512, 0, stream>>>(bsum, nscan);
  scan_final<<<nscan, 256, 0, stream>>>(deg, bsum, rp, cur, Nn, E);
  scatter_k<<<(E+255)/256, 256, 0, stream>>>(dstv, cur, eids, E);

  // ---- lin1 + leaky_relu ----
  gemm128<64, true, false><<<(Nn+63)/64, 256, 0, stream>>>(
      x, W1, b1, nullptr, nullptr, hA, nullptr, nullptr, Nn);

  // ---- 3 GAT layers (gemm with fused attention dots) ----
  for (int l = 0; l < NL; ++l){
    gemm128<128, false, true><<<(Nn+63)/64, 256, 0, stream>>>(
        hA, gW + (size_t)l*128*128, nullptr, g_asrc + l*128, g_adst + l*128,
        hB, asN, adN, Nn);
    gat_agg<<<(Nn+3)/4, 256, 0, stream>>>(srcv, eids, rp, asN, adN, hB, g_b + l*128, hA, Nn);
  }

  // ---- readout ----
  pool_relu<<<G, 128, 0, stream>>>(hA, batch, pooled, Nn);
  gemm128<128, false, true><<<(Nn+63)/64, 256, 0, stream>>>(
      hA, mW, nullptr, m_asrc, m_asrc, hB, asN, asN, Nn);          // hs2 + as2
  gemm128<128, false, true><<<(G+63)/64, 256, 0, stream>>>(
      pooled, mW, nullptr, m_adst, m_adst, hd2, adN, adN, G);      // hd2 + ad2
  mol_agg<<<G, 128, 0, stream>>>(asN, adN, hB, batch, m_b, W2, b2, (float*)d_out, Nn);
}